// Round 1
// 131.807 us; speedup vs baseline: 1.0628x; 1.0628x over previous
//
#include <hip/hip_runtime.h>

// ---------- helpers ----------
static __device__ __forceinline__ float bf2f(unsigned short u) {
    return __uint_as_float(((unsigned int)u) << 16);
}
static __device__ __forceinline__ unsigned short f2bf(float f) {
    unsigned int x = __float_as_uint(f);
    unsigned int lsb = (x >> 16) & 1u;
    x += 0x7fffu + lsb;                 // round-to-nearest-even
    return (unsigned short)(x >> 16);
}

typedef __attribute__((ext_vector_type(8))) short short8;    // 8 bf16 = 4 VGPRs (MFMA A/B frag)
typedef __attribute__((ext_vector_type(4))) float floatx4;   // MFMA C/D frag

static __device__ __forceinline__ short8 ldg8(const unsigned short* p) {
    short8 v; __builtin_memcpy(&v, p, 16); return v;
}

// ======================================================================
// FRAGMENT-MAJOR LAYOUT for MFMA operands (16x16x32 bf16):
//   element (row r, k) -> group g=r>>4, fr=r&15, kc=k>>5, q4=(k>>3)&3, j=k&7
//   offset = (g*8 + kc)*512 + (q4*16 + fr)*8 + j      [512 shorts per frag-slot]
// A wave's fragment load = base + lane*8 -> 64 lanes x 16B contiguous = 1KB txn.
// ======================================================================

// ---------- repack: role-partitioned grid, all reads/writes coalesced ----------
__global__ __launch_bounds__(256) void repack_kernel(
    const float* e2p_Wq, const float* e2p_bq,
    const float* e2p_Wk, const float* e2p_bk,
    const float* e2p_Wv, const float* e2p_bv,
    const float* e2p_Wo, const float* e2p_bo,
    const float* p2e_Wq, const float* p2e_bq,
    const float* p2e_Wk, const float* p2e_bk,
    const float* p2e_Wv, const float* p2e_bv,
    const float* p2e_Wo, const float* p2e_bo,
    const float* eeg, const float* pps,
    unsigned short* Wpack, unsigned short* Wopack, float* bias_pack, float* bias2,
    unsigned short* Abf)
{
    __shared__ unsigned short tr[2048];   // 4 KB transpose buffer (activation blocks)
    const int bid = blockIdx.x, tid = threadIdx.x;

    if (bid < 2048) {
        // --- activations: block = (g = bid>>1, kc_half = (bid&1)*4) ---
        const int g = bid >> 1, kc_half = (bid & 1) * 4;
        const int inp = g >> 9;
        const int m = (g & 511) * 16 + (tid >> 4);       // per-input row
        const int k8 = kc_half * 4 + (tid & 15);         // 8-elem k-slot
        const float* src = inp ? pps : eeg;
        float v[8];
        __builtin_memcpy(v, src + (long)m * 256 + k8 * 8, 32);   // coalesced 32B
        unsigned short o[8];
        #pragma unroll
        for (int j = 0; j < 8; ++j) o[j] = f2bf(v[j]);
        const int k8l = tid & 15;
        __builtin_memcpy(&tr[(k8l >> 2) * 512 + ((k8l & 3) * 16 + (tid >> 4)) * 8], o, 16);
        __syncthreads();
        unsigned short t[8];
        __builtin_memcpy(t, &tr[tid * 8], 16);
        __builtin_memcpy(Abf + inp * 2097152 + ((g & 511) * 8 + kc_half) * 512 + tid * 8, t, 16);  // linear 4KB
        return;
    }
    if (bid < 2240) {
        // --- QKV weights: 49152 slots; n_lo fastest for coalescing ---
        int idx = (bid - 2048) * 256 + tid;
        int inp = idx / 24576, r = idx % 24576;
        int n = (r & 15) | ((r >> 9) << 4);              // 0..767
        int k8 = (r >> 4) & 31;
        int kc = k8 >> 2, q4 = k8 & 3, kb = k8 * 8;
        int proj = n / 256, h = (n % 256) / 32, e = n % 32;
        const float* W;
        if (inp == 0) W = (proj == 0) ? e2p_Wq : (proj == 1) ? p2e_Wk : p2e_Wv;
        else          W = (proj == 0) ? p2e_Wq : (proj == 1) ? e2p_Wk : e2p_Wv;
        unsigned short o[8];
        #pragma unroll
        for (int j = 0; j < 8; ++j) o[j] = f2bf(W[h * 8192 + (kb + j) * 32 + e]);
        __builtin_memcpy(Wpack + inp * 196608 + ((n >> 4) * 8 + kc) * 512 + (q4 * 16 + (n & 15)) * 8, o, 16);
        return;
    }
    if (bid < 2304) {
        // --- Wo: 16384 slots (row n of Wo^T = col n of Wo) ---
        int i2 = (bid - 2240) * 256 + tid;
        int dir = i2 / 8192, r = i2 % 8192;
        int n = (r & 15) | ((r >> 9) << 4);              // 0..255
        int k8 = (r >> 4) & 31;
        int kc = k8 >> 2, q4 = k8 & 3, kb = k8 * 8;
        const float* Wo = dir ? p2e_Wo : e2p_Wo;
        unsigned short o[8];
        #pragma unroll
        for (int j = 0; j < 8; ++j) o[j] = f2bf(Wo[(kb + j) * 256 + n]);
        __builtin_memcpy(Wopack + dir * 65536 + ((n >> 4) * 8 + kc) * 512 + (q4 * 16 + (n & 15)) * 8, o, 16);
        return;
    }
    // --- biases ---
    {
        int idx = (bid - 2304) * 256 + tid;   // 0..2047
        if (idx < 1536) {
            int inp = idx / 768, n = idx % 768;
            int proj = n / 256, he = n % 256;
            const float* bsrc;
            if (inp == 0) bsrc = (proj == 0) ? e2p_bq : (proj == 1) ? p2e_bk : p2e_bv;
            else          bsrc = (proj == 0) ? p2e_bq : (proj == 1) ? e2p_bk : e2p_bv;
            bias_pack[idx] = bsrc[he];
        } else {
            int j = idx - 1536;
            int dir = j / 256, n = j % 256;
            bias2[j] = (dir == 0 ? e2p_bo : p2e_bo)[n];
        }
    }
}

// ---------- MFMA GEMM, barrier-free K-loop, frag-major operands (unchanged) ----------
__global__ __launch_bounds__(256) void mfma_gemm_kernel(
    const unsigned short* __restrict__ A0, const unsigned short* __restrict__ A1,
    const unsigned short* __restrict__ B0f, const unsigned short* __restrict__ B1f,
    const float* __restrict__ bias0, const float* __restrict__ bias1,
    unsigned short* __restrict__ C0, unsigned short* __restrict__ C1,
    int N)
{
    __shared__ __align__(16) unsigned short Cs[128][136];   // epilogue only

    const int z = blockIdx.z;
    const unsigned short* A = z ? A1 : A0;
    const unsigned short* Bf = z ? B1f : B0f;
    const float* bias = z ? bias1 : bias0;
    unsigned short* C = z ? C1 : C0;

    const int tid = threadIdx.x;
    const long m0 = (long)blockIdx.x * 128;
    const int n0 = blockIdx.y * 128;

    const int lane = tid & 63;
    const int wv = tid >> 6;
    const int wm = (wv >> 1) * 64, wn = (wv & 1) * 64;
    const int fr = lane & 15, q4 = lane >> 4;

    const unsigned short* Aw = A + ((blockIdx.x * 8 + (wm >> 4)) * 8) * 512 + lane * 8;
    const unsigned short* Bw = Bf + ((blockIdx.y * 8 + (wn >> 4)) * 8) * 512 + lane * 8;

    floatx4 acc[4][4] = {};
    short8 af[2][4], bf_[2][4];

    #pragma unroll
    for (int i = 0; i < 4; ++i) af[0][i] = ldg8(Aw + i * 4096);
    #pragma unroll
    for (int j = 0; j < 4; ++j) bf_[0][j] = ldg8(Bw + j * 4096);

    #pragma unroll
    for (int kc = 0; kc < 8; ++kc) {
        const int cur = kc & 1, nxt = cur ^ 1;
        if (kc < 7) {
            #pragma unroll
            for (int i = 0; i < 4; ++i) af[nxt][i] = ldg8(Aw + (i * 8 + kc + 1) * 512);
            #pragma unroll
            for (int j = 0; j < 4; ++j) bf_[nxt][j] = ldg8(Bw + (j * 8 + kc + 1) * 512);
        }
        #pragma unroll
        for (int i = 0; i < 4; ++i)
            #pragma unroll
            for (int j = 0; j < 4; ++j)
                acc[i][j] = __builtin_amdgcn_mfma_f32_16x16x32_bf16(af[cur][i], bf_[cur][j], acc[i][j], 0, 0, 0);
    }

    float bj[4];
    #pragma unroll
    for (int j = 0; j < 4; ++j) bj[j] = bias[n0 + wn + j * 16 + fr];

    const int cr0 = wm + (q4 << 2);
    #pragma unroll
    for (int i = 0; i < 4; ++i)
        #pragma unroll
        for (int j = 0; j < 4; ++j)
            #pragma unroll
            for (int r = 0; r < 4; ++r)
                Cs[cr0 + i * 16 + r][wn + j * 16 + fr] = f2bf(acc[i][j][r] + bj[j]);
    __syncthreads();

    const int rr = tid >> 4, cc = (tid & 15) * 8;
    #pragma unroll
    for (int p = 0; p < 8; ++p) {
        int r = p * 16 + rr;
        unsigned short tmp[8];
        __builtin_memcpy(tmp, &Cs[r][cc], 16);
        __builtin_memcpy(C + (m0 + r) * N + n0 + cc, tmp, 16);
    }
}

// ---------- fused MFMA attention + output projection, 32-row s-tile ----------
// Block = (s-tile of 32, b, dir), 512 thr = 8 waves, one head per wave.
// K/V rows r=0..63 are seq positions p = s0-15+r (OOB rows = bias vectors, NOT
// masked — reference pads kv BEFORE projection).  Band: 0 <= jc - i <= 30.
//
// 3 barriers total:
//  (1) staging complete
//  (2) all score reads of K done -> P (bf16) may overwrite K region
//  (3) att tile (As) complete -> outproj reads
// As is aliased over the V region AT THE SAME COLUMN OFFSETS: wave wv writes
// only cols [32*wv,32*wv+32) of As, which are exactly the V columns that only
// wave wv reads (per-head columns) -> no barrier needed between PV and As
// writes (same-wave ordering guaranteed by the oacc data dependence on the V
// reads). Outproj result + bias stores straight to global (no Os round-trip).
#define KVSTR 264
#define PSTR 72
__global__ __launch_bounds__(512, 4) void attn_out_kernel(
    const unsigned short* __restrict__ Y, const float* __restrict__ bias_pack,
    const unsigned short* __restrict__ Wopack, const float* __restrict__ bias2,
    float* __restrict__ out)
{
    // region0: K [64][264] (16896 us) / P [8][32][72] (18432 us)  -> 18432 ushorts
    // region1: V [64][264] / As [32][264]                          -> 16896 ushorts
    __shared__ __align__(16) unsigned short smem[18432 + 16896];   // 70656 B
    unsigned short* Ks = smem;
    unsigned short* Vs = smem + 18432;
    unsigned short (*Ps)[32][PSTR] = (unsigned short(*)[32][PSTR])smem;
    unsigned short (*As)[KVSTR] = (unsigned short(*)[KVSTR])(smem + 18432);

    const int s0 = blockIdx.x * 32;
    const int b = blockIdx.y, dir = blockIdx.z;
    const int kvinp = 1 - dir;
    const int tid = threadIdx.x;

    const float* bkv = bias_pack + kvinp * 768;
    const long kvbase = ((long)kvinp * 8192 + b * 2048) * 768;

    // ---- stage K and V (64 rows each), 32 e per task, fully coalesced ----
    {
        const int r = tid >> 3, seg = (tid & 7) * 32;
        const int p = s0 - 15 + r;
        unsigned short tmp[32];
        if (p >= 0 && p < 2048) {
            __builtin_memcpy(tmp, Y + kvbase + (long)p * 768 + 256 + seg, 64);
        } else {
            #pragma unroll
            for (int j = 0; j < 32; ++j) tmp[j] = f2bf(bkv[256 + seg + j]);
        }
        __builtin_memcpy(&Ks[r * KVSTR + seg], tmp, 64);
        if (p >= 0 && p < 2048) {
            __builtin_memcpy(tmp, Y + kvbase + (long)p * 768 + 512 + seg, 64);
        } else {
            #pragma unroll
            for (int j = 0; j < 32; ++j) tmp[j] = f2bf(bkv[512 + seg + j]);
        }
        __builtin_memcpy(&Vs[r * KVSTR + seg], tmp, 64);
    }

    // ---- Q fragments (A-layout) direct from global: rows s0..s0+31 ----
    const int lane = tid & 63;
    const int wv = tid >> 6;                    // head index 0..7
    const int fr = lane & 15, q4 = lane >> 4;
    short8 aq[2];
    #pragma unroll
    for (int it = 0; it < 2; ++it)
        aq[it] = ldg8(Y + ((long)dir * 8192 + b * 2048 + s0 + it * 16 + fr) * 768 + wv * 32 + q4 * 8);

    __syncthreads();   // (1) staging complete

    // ---- scores: S[32 s][64 kv]; band structure -> only 6 of 8 MFMAs ----
    // it=0 needs kvt 0..2, it=1 needs kvt 1..3 (others fully masked)
    floatx4 sacc[2][3] = {};
    #pragma unroll
    for (int kvt = 0; kvt < 4; ++kvt) {
        short8 bk_ = *(const short8*)&Ks[(kvt * 16 + fr) * KVSTR + wv * 32 + q4 * 8];
        if (kvt < 3) sacc[0][kvt]     = __builtin_amdgcn_mfma_f32_16x16x32_bf16(aq[0], bk_, sacc[0][kvt], 0, 0, 0);
        if (kvt > 0) sacc[1][kvt - 1] = __builtin_amdgcn_mfma_f32_16x16x32_bf16(aq[1], bk_, sacc[1][kvt - 1], 0, 0, 0);
    }

    // ---- band mask + softmax (row i = it*16 + q4*4 + reg; col jc = (it+kt)*16 + fr) ----
    float sv[2][3][4];
    float rs[2][4];
    #pragma unroll
    for (int it = 0; it < 2; ++it) {
        float mx[4] = {-3.0e38f, -3.0e38f, -3.0e38f, -3.0e38f};
        #pragma unroll
        for (int kt = 0; kt < 3; ++kt)
            #pragma unroll
            for (int reg = 0; reg < 4; ++reg) {
                int i = it * 16 + q4 * 4 + reg;
                int jc = (it + kt) * 16 + fr;
                int d = jc - i;
                float x = (d >= 0 && d <= 30) ? sacc[it][kt][reg] * 0.17677669529663687f : -3.0e38f;
                sv[it][kt][reg] = x;
                mx[reg] = fmaxf(mx[reg], x);
            }
        #pragma unroll
        for (int off = 1; off < 16; off <<= 1)
            #pragma unroll
            for (int reg = 0; reg < 4; ++reg)
                mx[reg] = fmaxf(mx[reg], __shfl_xor(mx[reg], off));
        float ps[4] = {};
        #pragma unroll
        for (int kt = 0; kt < 3; ++kt)
            #pragma unroll
            for (int reg = 0; reg < 4; ++reg) {
                float e = __expf(sv[it][kt][reg] - mx[reg]);
                sv[it][kt][reg] = e;
                ps[reg] += e;
            }
        #pragma unroll
        for (int off = 1; off < 16; off <<= 1)
            #pragma unroll
            for (int reg = 0; reg < 4; ++reg)
                ps[reg] += __shfl_xor(ps[reg], off);
        #pragma unroll
        for (int reg = 0; reg < 4; ++reg) rs[it][reg] = 1.0f / ps[reg];
    }

    __syncthreads();   // (2) all score reads of K done; P may overwrite K region

    // ---- P -> LDS bf16 (fully-masked kvt written as zero for the K=64 PV) ----
    #pragma unroll
    for (int it = 0; it < 2; ++it)
        #pragma unroll
        for (int reg = 0; reg < 4; ++reg) {
            int i = it * 16 + q4 * 4 + reg;
            #pragma unroll
            for (int kt = 0; kt < 3; ++kt)
                Ps[wv][i][(it + kt) * 16 + fr] = f2bf(sv[it][kt][reg]);
            Ps[wv][i][(it == 0 ? 48 : 0) + fr] = 0;
        }
    // same-wave LDS RAW (P write -> P read) ordered by lgkmcnt; no barrier needed.

    // ---- PV: O[32 s][32 e] via 8 MFMAs (A = own P rows, B = V^T strided) ----
    floatx4 oacc[2][2] = {};
    #pragma unroll
    for (int ch = 0; ch < 2; ++ch) {
        short8 ap0 = *(const short8*)&Ps[wv][fr][ch * 32 + q4 * 8];
        short8 ap1 = *(const short8*)&Ps[wv][16 + fr][ch * 32 + q4 * 8];
        #pragma unroll
        for (int et = 0; et < 2; ++et) {
            short8 bv;
            #pragma unroll
            for (int j = 0; j < 8; ++j)
                bv[j] = (short)Vs[(ch * 32 + q4 * 8 + j) * KVSTR + wv * 32 + et * 16 + fr];
            oacc[0][et] = __builtin_amdgcn_mfma_f32_16x16x32_bf16(ap0, bv, oacc[0][et], 0, 0, 0);
            oacc[1][et] = __builtin_amdgcn_mfma_f32_16x16x32_bf16(ap1, bv, oacc[1][et], 0, 0, 0);
        }
    }

    // ---- att tile over V region, SAME column offsets (per-head cols -> no barrier) ----
    #pragma unroll
    for (int it = 0; it < 2; ++it)
        #pragma unroll
        for (int et = 0; et < 2; ++et)
            #pragma unroll
            for (int reg = 0; reg < 4; ++reg)
                As[it * 16 + q4 * 4 + reg][wv * 32 + et * 16 + fr] = f2bf(oacc[it][et][reg] * rs[it][reg]);

    __syncthreads();   // (3) att tile complete

    // ---- output projection: out[32 x 256] = att @ Wo^T + bias2, direct global store ----
    const unsigned short* Wo = Wopack + dir * 65536 + lane * 8;
    const int nw = wv * 32;
    floatx4 oa[2][2] = {};
    #pragma unroll
    for (int kc = 0; kc < 8; ++kc) {
        short8 ap0 = *(const short8*)&As[fr][kc * 32 + q4 * 8];
        short8 ap1 = *(const short8*)&As[16 + fr][kc * 32 + q4 * 8];
        #pragma unroll
        for (int j = 0; j < 2; ++j) {
            short8 bw = ldg8(Wo + ((wv * 2 + j) * 8 + kc) * 512);   // coalesced frag load
            oa[0][j] = __builtin_amdgcn_mfma_f32_16x16x32_bf16(ap0, bw, oa[0][j], 0, 0, 0);
            oa[1][j] = __builtin_amdgcn_mfma_f32_16x16x32_bf16(ap1, bw, oa[1][j], 0, 0, 0);
        }
    }

    float bj[2];
    #pragma unroll
    for (int j = 0; j < 2; ++j) bj[j] = bias2[dir * 256 + nw + j * 16 + fr];

    float* obase = out + (long)dir * 2097152 + ((long)b * 2048 + s0) * 256;
    #pragma unroll
    for (int it = 0; it < 2; ++it)
        #pragma unroll
        for (int j = 0; j < 2; ++j)
            #pragma unroll
            for (int reg = 0; reg < 4; ++reg)
                obase[(it * 16 + q4 * 4 + reg) * 256 + nw + j * 16 + fr] = oa[it][j][reg] + bj[j];
}

// ---------- launch ----------
extern "C" void kernel_launch(void* const* d_in, const int* in_sizes, int n_in,
                              void* d_out, int out_size, void* d_ws, size_t ws_size,
                              hipStream_t stream)
{
    float* out = (float*)d_out;

    char* ws = (char*)d_ws;
    unsigned short* Wpack   = (unsigned short*)(ws + 0);          // 786432 B (frag-major)
    unsigned short* Wopack  = (unsigned short*)(ws + 786432);     // 262144 B (frag-major)
    float*          biasP   = (float*)(ws + 1048576);             // 6144 B
    float*          bias2   = (float*)(ws + 1054720);             // 2048 B
    unsigned short* Y       = (unsigned short*)(ws + 1056768);    // 25165824 B (row-major)
    unsigned short* Abf     = (unsigned short*)(ws + 26222592);   // 8388608 B (frag-major)

    repack_kernel<<<2312, 256, 0, stream>>>(
        (const float*)d_in[2],  (const float*)d_in[3],
        (const float*)d_in[4],  (const float*)d_in[5],
        (const float*)d_in[6],  (const float*)d_in[7],
        (const float*)d_in[8],  (const float*)d_in[9],
        (const float*)d_in[10], (const float*)d_in[11],
        (const float*)d_in[12], (const float*)d_in[13],
        (const float*)d_in[14], (const float*)d_in[15],
        (const float*)d_in[16], (const float*)d_in[17],
        (const float*)d_in[0],  (const float*)d_in[1],
        Wpack, Wopack, biasP, bias2, Abf);

    // fused QKV projection: Abf(frag-major) @ Wpack + bias -> Y (bf16 row-major)
    mfma_gemm_kernel<<<dim3(64, 6, 2), 256, 0, stream>>>(
        Abf, Abf + 2097152, Wpack, Wpack + 196608, biasP, biasP + 768,
        Y, Y + 8192 * 768, 768);

    // fused windowed attention + output projection -> d_out (fp32)
    attn_out_kernel<<<dim3(64, 4, 2), 512, 0, stream>>>(Y, biasP, Wopack, bias2, out);
}

// Round 3
// 129.022 us; speedup vs baseline: 1.0857x; 1.0216x over previous
//
#include <hip/hip_runtime.h>

// ---------- helpers ----------
static __device__ __forceinline__ unsigned short f2bf(float f) {
    unsigned int x = __float_as_uint(f);
    unsigned int lsb = (x >> 16) & 1u;
    x += 0x7fffu + lsb;                 // round-to-nearest-even
    return (unsigned short)(x >> 16);
}

typedef __attribute__((ext_vector_type(8))) short short8;    // 8 bf16 = 4 VGPRs (MFMA A/B frag)
typedef __attribute__((ext_vector_type(4))) float floatx4;   // MFMA C/D frag

static __device__ __forceinline__ short8 ldg8(const unsigned short* p) {
    short8 v; __builtin_memcpy(&v, p, 16); return v;
}

// ======================================================================
// FRAGMENT-MAJOR WEIGHT LAYOUT (16x16x32 bf16), unchanged:
//   element (n, k) -> group g=n>>4, fr=n&15, kc=k>>5, q4=(k>>3)&3, j=k&7
//   offset = (g*8 + kc)*512 + (q4*16 + fr)*8 + j
// A wave's fragment load = base + lane*8 -> 64 lanes x 16B contiguous.
// ======================================================================

// ---------- repack: weights + biases ONLY ----------
__global__ __launch_bounds__(256) void repack_w(
    const float* e2p_Wq, const float* e2p_bq,
    const float* e2p_Wk, const float* e2p_bk,
    const float* e2p_Wv, const float* e2p_bv,
    const float* e2p_Wo, const float* e2p_bo,
    const float* p2e_Wq, const float* p2e_bq,
    const float* p2e_Wk, const float* p2e_bk,
    const float* p2e_Wv, const float* p2e_bv,
    const float* p2e_Wo, const float* p2e_bo,
    unsigned short* Wpack, unsigned short* Wopack, float* bias_pack, float* bias2)
{
    const int bid = blockIdx.x, tid = threadIdx.x;

    if (bid < 192) {
        // --- QKV weights: 49152 slots; n_lo fastest for coalescing ---
        int idx = bid * 256 + tid;
        int inp = idx / 24576, r = idx % 24576;
        int n = (r & 15) | ((r >> 9) << 4);              // 0..767
        int k8 = (r >> 4) & 31;
        int kc = k8 >> 2, q4 = k8 & 3, kb = k8 * 8;
        int proj = n / 256, h = (n % 256) / 32, e = n % 32;
        const float* W;
        if (inp == 0) W = (proj == 0) ? e2p_Wq : (proj == 1) ? p2e_Wk : p2e_Wv;
        else          W = (proj == 0) ? p2e_Wq : (proj == 1) ? e2p_Wk : e2p_Wv;
        unsigned short o[8];
        #pragma unroll
        for (int j = 0; j < 8; ++j) o[j] = f2bf(W[h * 8192 + (kb + j) * 32 + e]);
        __builtin_memcpy(Wpack + inp * 196608 + ((n >> 4) * 8 + kc) * 512 + (q4 * 16 + (n & 15)) * 8, o, 16);
        return;
    }
    if (bid < 256) {
        // --- Wo: 16384 slots (row n of Wo^T = col n of Wo) ---
        int i2 = (bid - 192) * 256 + tid;
        int dir = i2 / 8192, r = i2 % 8192;
        int n = (r & 15) | ((r >> 9) << 4);              // 0..255
        int k8 = (r >> 4) & 31;
        int kc = k8 >> 2, q4 = k8 & 3, kb = k8 * 8;
        const float* Wo = dir ? p2e_Wo : e2p_Wo;
        unsigned short o[8];
        #pragma unroll
        for (int j = 0; j < 8; ++j) o[j] = f2bf(Wo[(kb + j) * 256 + n]);
        __builtin_memcpy(Wopack + dir * 65536 + ((n >> 4) * 8 + kc) * 512 + (q4 * 16 + (n & 15)) * 8, o, 16);
        return;
    }
    // --- biases ---
    {
        int idx = (bid - 256) * 256 + tid;   // 0..2047
        if (idx < 1536) {
            int inp = idx / 768, n = idx % 768;
            int proj = n / 256, he = n % 256;
            const float* bsrc;
            if (inp == 0) bsrc = (proj == 0) ? e2p_bq : (proj == 1) ? p2e_bk : p2e_bv;
            else          bsrc = (proj == 0) ? p2e_bq : (proj == 1) ? e2p_bk : e2p_bv;
            bias_pack[idx] = bsrc[he];
        } else {
            int j = idx - 1536;
            int dir = j / 256, n = j % 256;
            bias2[j] = (dir == 0 ? e2p_bo : p2e_bo)[n];
        }
    }
}

// ---------- fully fused: QKV projection + windowed attention + output projection ----------
// Block = (s-tile of 32, b, dir), 512 thr = 8 waves, one head per wave.
// RACE FIX vs prev round: Qw now has its OWN per-wave region (never overwritten).
// Every remaining same-wave LDS reuse carries a TRUE data dependence:
//   - P overwrites the Kw region, but each P ds_write's data operand comes from
//     score MFMAs that consumed every overlapping Kw ds_read (verified per
//     overlap range: it=0 P rows [0,1143] overlap only bk0/bk1 read ranges,
//     it=1 P rows [1152,2295] only bk1/bk2/bk3 — all dep-covered), so the
//     write cannot issue before those reads completed.
//   - All write->read (RAW) reuses rely on in-order same-wave DS execution
//     (validated pattern from prior passing rounds).
// Cross-wave sharing (Xq/Xkv/As) is barrier-protected: 3 block barriers.
//
// LDS map (shorts), total 74496 = 148,992 B (1 block/CU):
//   [0,8448)        Xq  [32][264]   (aliased by att tile As[32][264] after barrier 2)
//   [8448,25344)    Xkv [64][264]
//   [25344,74496)   per-wave scratch, 6144 each:
//                     Qw [32][40] = 1280   (never overwritten)
//                     Kw [64][40] = 2560   (P [32][72] = 2304 aliases it later)
//                     Vt [32][72] = 2304   (V transposed: Vt[e][kv])
#define XSTR 264
#define KSTR 40
#define PSTR 72
#define VTSTR 72
#define XKV_OFF 8448
#define SCR_OFF 25344
#define SCR_SZ 6144
__global__ __launch_bounds__(512, 2) void fused_attn(
    const float* __restrict__ eeg, const float* __restrict__ pps,
    const unsigned short* __restrict__ Wpack, const float* __restrict__ biasP,
    const unsigned short* __restrict__ Wopack, const float* __restrict__ bias2,
    float* __restrict__ out)
{
    __shared__ __align__(16) unsigned short smem[74496];   // 148992 B
    unsigned short* Xq  = smem;
    unsigned short* Xkv = smem + XKV_OFF;

    const int s0 = blockIdx.x * 32;
    const int b = blockIdx.y, dir = blockIdx.z;
    const int kvinp = 1 - dir;
    const int tid = threadIdx.x;
    const int lane = tid & 63;
    const int wv = tid >> 6;                    // head index 0..7
    const int fr = lane & 15, q4 = lane >> 4;

    unsigned short* Qw = smem + SCR_OFF + wv * SCR_SZ;   // [32][40]
    unsigned short* Kw = Qw + 1280;                      // [64][40]; P [32][72] aliases later
    unsigned short* Vt = Qw + 3840;                      // [32][72]

    // per-wave bias scalars (col = j*16+fr)
    float bqq[2], bkk[2], bvv[2], bj2[2];
    #pragma unroll
    for (int j = 0; j < 2; ++j) {
        bqq[j] = biasP[dir * 768 + wv * 32 + j * 16 + fr];
        bkk[j] = biasP[kvinp * 768 + 256 + wv * 32 + j * 16 + fr];
        bvv[j] = biasP[kvinp * 768 + 512 + wv * 32 + j * 16 + fr];
        bj2[j] = bias2[dir * 256 + wv * 32 + j * 16 + fr];
    }

    // ---- stage X tiles (fp32 -> bf16), coalesced 128B per thread ----
    {
        const int r = tid >> 3, seg = (tid & 7) * 32;    // r 0..63
        const int p = s0 - 15 + r;
        const float* Xkvsrc = dir ? eeg : pps;
        unsigned short o[32];
        if (p >= 0 && p < 2048) {
            float v[32];
            __builtin_memcpy(v, Xkvsrc + ((long)b * 2048 + p) * 256 + seg, 128);
            #pragma unroll
            for (int j = 0; j < 32; ++j) o[j] = f2bf(v[j]);
        } else {
            #pragma unroll
            for (int j = 0; j < 32; ++j) o[j] = 0;       // zero-pad BEFORE projection
        }
        __builtin_memcpy(&Xkv[r * XSTR + seg], o, 64);
        if (tid < 256) {                                 // Xq rows 0..31, always in-bounds
            const float* Xqsrc = dir ? pps : eeg;
            float v[32];
            __builtin_memcpy(v, Xqsrc + ((long)b * 2048 + s0 + r) * 256 + seg, 128);
            unsigned short o2[32];
            #pragma unroll
            for (int j = 0; j < 32; ++j) o2[j] = f2bf(v[j]);
            __builtin_memcpy(&Xq[r * XSTR + seg], o2, 64);
        }
    }
    __syncthreads();   // (1) staging complete

    const unsigned short* WB = Wpack + (long)kvinp * 196608 + lane * 8;
    const unsigned short* WQ = Wpack + (long)dir * 196608 + lane * 8;

    // ---- Q slice: [32 s][32 e] = Xq @ Wq(head) ----
    floatx4 qacc[2][2] = {};
    #pragma unroll
    for (int kc = 0; kc < 8; ++kc) {
        short8 a0 = *(const short8*)&Xq[(fr) * XSTR + kc * 32 + q4 * 8];
        short8 a1 = *(const short8*)&Xq[(16 + fr) * XSTR + kc * 32 + q4 * 8];
        #pragma unroll
        for (int j = 0; j < 2; ++j) {
            short8 bw = ldg8(WQ + ((2 * wv + j) * 8 + kc) * 512);
            qacc[0][j] = __builtin_amdgcn_mfma_f32_16x16x32_bf16(a0, bw, qacc[0][j], 0, 0, 0);
            qacc[1][j] = __builtin_amdgcn_mfma_f32_16x16x32_bf16(a1, bw, qacc[1][j], 0, 0, 0);
        }
    }
    // Q C-frags (+bias) -> dedicated Qw scratch (never overwritten)
    #pragma unroll
    for (int it = 0; it < 2; ++it)
        #pragma unroll
        for (int j = 0; j < 2; ++j)
            #pragma unroll
            for (int reg = 0; reg < 4; ++reg)
                Qw[(it * 16 + q4 * 4 + reg) * KSTR + j * 16 + fr] = f2bf(qacc[it][j][reg] + bqq[j]);

    // ---- K,V slices: [64 kv][32 e] = Xkv @ {Wk,Wv}(head), shared A-frags ----
    floatx4 kacc[4][2] = {}, vacc[4][2] = {};
    #pragma unroll
    for (int kc = 0; kc < 8; ++kc) {
        short8 ax[4];
        #pragma unroll
        for (int mi = 0; mi < 4; ++mi)
            ax[mi] = *(const short8*)&Xkv[(mi * 16 + fr) * XSTR + kc * 32 + q4 * 8];
        #pragma unroll
        for (int j = 0; j < 2; ++j) {
            short8 kb = ldg8(WB + ((16 + 2 * wv + j) * 8 + kc) * 512);
            short8 vb = ldg8(WB + ((32 + 2 * wv + j) * 8 + kc) * 512);
            #pragma unroll
            for (int mi = 0; mi < 4; ++mi) {
                kacc[mi][j] = __builtin_amdgcn_mfma_f32_16x16x32_bf16(ax[mi], kb, kacc[mi][j], 0, 0, 0);
                vacc[mi][j] = __builtin_amdgcn_mfma_f32_16x16x32_bf16(ax[mi], vb, vacc[mi][j], 0, 0, 0);
            }
        }
    }
    // K C-frags (+bias) -> Kw rows 0..63
    #pragma unroll
    for (int mi = 0; mi < 4; ++mi)
        #pragma unroll
        for (int j = 0; j < 2; ++j)
            #pragma unroll
            for (int reg = 0; reg < 4; ++reg)
                Kw[(mi * 16 + q4 * 4 + reg) * KSTR + j * 16 + fr] = f2bf(kacc[mi][j][reg] + bkk[j]);
    // V C-frags (+bias) -> Vt TRANSPOSED (Vt[e][kv]); 4 regs = 8B contiguous
    #pragma unroll
    for (int mi = 0; mi < 4; ++mi)
        #pragma unroll
        for (int j = 0; j < 2; ++j) {
            unsigned short t4[4];
            #pragma unroll
            for (int reg = 0; reg < 4; ++reg) t4[reg] = f2bf(vacc[mi][j][reg] + bvv[j]);
            __builtin_memcpy(&Vt[(j * 16 + fr) * VTSTR + mi * 16 + q4 * 4], t4, 8);
        }

    // ---- scores: S[32 s][64 kv]; band structure -> 6 of 8 MFMAs ----
    short8 aq0 = *(const short8*)&Qw[fr * KSTR + q4 * 8];
    short8 aq1 = *(const short8*)&Qw[(16 + fr) * KSTR + q4 * 8];
    floatx4 sacc[2][3] = {};
    #pragma unroll
    for (int kvt = 0; kvt < 4; ++kvt) {
        short8 bk_ = *(const short8*)&Kw[(kvt * 16 + fr) * KSTR + q4 * 8];
        if (kvt < 3) sacc[0][kvt]     = __builtin_amdgcn_mfma_f32_16x16x32_bf16(aq0, bk_, sacc[0][kvt], 0, 0, 0);
        if (kvt > 0) sacc[1][kvt - 1] = __builtin_amdgcn_mfma_f32_16x16x32_bf16(aq1, bk_, sacc[1][kvt - 1], 0, 0, 0);
    }

    // ---- band mask + softmax (row i = it*16+q4*4+reg; col jc = (it+kt)*16+fr) ----
    float sv[2][3][4];
    float rs[2][4];
    #pragma unroll
    for (int it = 0; it < 2; ++it) {
        float mx[4] = {-3.0e38f, -3.0e38f, -3.0e38f, -3.0e38f};
        #pragma unroll
        for (int kt = 0; kt < 3; ++kt)
            #pragma unroll
            for (int reg = 0; reg < 4; ++reg) {
                int i = it * 16 + q4 * 4 + reg;
                int jc = (it + kt) * 16 + fr;
                int d = jc - i;
                float x = (d >= 0 && d <= 30) ? sacc[it][kt][reg] * 0.17677669529663687f : -3.0e38f;
                sv[it][kt][reg] = x;
                mx[reg] = fmaxf(mx[reg], x);
            }
        #pragma unroll
        for (int off = 1; off < 16; off <<= 1)
            #pragma unroll
            for (int reg = 0; reg < 4; ++reg)
                mx[reg] = fmaxf(mx[reg], __shfl_xor(mx[reg], off));
        float ps[4] = {};
        #pragma unroll
        for (int kt = 0; kt < 3; ++kt)
            #pragma unroll
            for (int reg = 0; reg < 4; ++reg) {
                float e = __expf(sv[it][kt][reg] - mx[reg]);
                sv[it][kt][reg] = e;
                ps[reg] += e;
            }
        #pragma unroll
        for (int off = 1; off < 16; off <<= 1)
            #pragma unroll
            for (int reg = 0; reg < 4; ++reg)
                ps[reg] += __shfl_xor(ps[reg], off);
        #pragma unroll
        for (int reg = 0; reg < 4; ++reg) rs[it][reg] = 1.0f / ps[reg];
    }

    // ---- P -> Kw-alias as [32][72] bf16 (every overlapping write is
    //      data-dependent on the K reads it may clobber; see header) ----
    unsigned short* Pb = Kw;
    #pragma unroll
    for (int it = 0; it < 2; ++it)
        #pragma unroll
        for (int reg = 0; reg < 4; ++reg) {
            int i = it * 16 + q4 * 4 + reg;
            #pragma unroll
            for (int kt = 0; kt < 3; ++kt)
                Pb[i * PSTR + (it + kt) * 16 + fr] = f2bf(sv[it][kt][reg]);
            Pb[i * PSTR + (it == 0 ? 48 : 0) + fr] = 0;
        }

    // ---- PV: O[32 s][32 e] via 8 MFMAs (A = P rows, B = Vt rows: 16B reads) ----
    floatx4 oacc[2][2] = {};
    #pragma unroll
    for (int ch = 0; ch < 2; ++ch) {
        short8 ap0 = *(const short8*)&Pb[fr * PSTR + ch * 32 + q4 * 8];
        short8 ap1 = *(const short8*)&Pb[(16 + fr) * PSTR + ch * 32 + q4 * 8];
        #pragma unroll
        for (int et = 0; et < 2; ++et) {
            short8 bv = *(const short8*)&Vt[(et * 16 + fr) * VTSTR + ch * 32 + q4 * 8];
            oacc[0][et] = __builtin_amdgcn_mfma_f32_16x16x32_bf16(ap0, bv, oacc[0][et], 0, 0, 0);
            oacc[1][et] = __builtin_amdgcn_mfma_f32_16x16x32_bf16(ap1, bv, oacc[1][et], 0, 0, 0);
        }
    }

    __syncthreads();   // (2) all waves done with Xq reads; att tile may alias Xq

    // ---- att tile [32][264] over Xq region ----
    unsigned short (*As)[XSTR] = (unsigned short(*)[XSTR])smem;
    #pragma unroll
    for (int it = 0; it < 2; ++it)
        #pragma unroll
        for (int et = 0; et < 2; ++et)
            #pragma unroll
            for (int reg = 0; reg < 4; ++reg)
                As[it * 16 + q4 * 4 + reg][wv * 32 + et * 16 + fr] = f2bf(oacc[it][et][reg] * rs[it][reg]);

    __syncthreads();   // (3) att tile complete

    // ---- output projection: out[32 x 256] = att @ Wo^T + bias2, direct store ----
    const unsigned short* Wo = Wopack + dir * 65536 + lane * 8;
    floatx4 oa[2][2] = {};
    #pragma unroll
    for (int kc = 0; kc < 8; ++kc) {
        short8 ap0 = *(const short8*)&As[fr][kc * 32 + q4 * 8];
        short8 ap1 = *(const short8*)&As[16 + fr][kc * 32 + q4 * 8];
        #pragma unroll
        for (int j = 0; j < 2; ++j) {
            short8 bw = ldg8(Wo + ((wv * 2 + j) * 8 + kc) * 512);
            oa[0][j] = __builtin_amdgcn_mfma_f32_16x16x32_bf16(ap0, bw, oa[0][j], 0, 0, 0);
            oa[1][j] = __builtin_amdgcn_mfma_f32_16x16x32_bf16(ap1, bw, oa[1][j], 0, 0, 0);
        }
    }

    float* obase = out + (long)dir * 2097152 + ((long)b * 2048 + s0) * 256;
    #pragma unroll
    for (int it = 0; it < 2; ++it)
        #pragma unroll
        for (int j = 0; j < 2; ++j)
            #pragma unroll
            for (int reg = 0; reg < 4; ++reg)
                obase[(it * 16 + q4 * 4 + reg) * 256 + wv * 32 + j * 16 + fr] = oa[it][j][reg] + bj2[j];
}

// ---------- launch ----------
extern "C" void kernel_launch(void* const* d_in, const int* in_sizes, int n_in,
                              void* d_out, int out_size, void* d_ws, size_t ws_size,
                              hipStream_t stream)
{
    float* out = (float*)d_out;

    char* ws = (char*)d_ws;
    unsigned short* Wpack   = (unsigned short*)(ws + 0);          // 786432 B (frag-major)
    unsigned short* Wopack  = (unsigned short*)(ws + 786432);     // 262144 B (frag-major)
    float*          biasP   = (float*)(ws + 1048576);             // 6144 B
    float*          bias2   = (float*)(ws + 1054720);             // 2048 B

    repack_w<<<264, 256, 0, stream>>>(
        (const float*)d_in[2],  (const float*)d_in[3],
        (const float*)d_in[4],  (const float*)d_in[5],
        (const float*)d_in[6],  (const float*)d_in[7],
        (const float*)d_in[8],  (const float*)d_in[9],
        (const float*)d_in[10], (const float*)d_in[11],
        (const float*)d_in[12], (const float*)d_in[13],
        (const float*)d_in[14], (const float*)d_in[15],
        (const float*)d_in[16], (const float*)d_in[17],
        Wpack, Wopack, biasP, bias2);

    // fully fused QKV proj + windowed attention + output proj -> d_out (fp32)
    fused_attn<<<dim3(64, 4, 2), 512, 0, stream>>>(
        (const float*)d_in[0], (const float*)d_in[1],
        Wpack, biasP, Wopack, bias2, out);
}